// Round 8
// baseline (111.840 us; speedup 1.0000x reference)
//
#include <hip/hip_runtime.h>
#include <hip/hip_bf16.h>

// CapsuleNet dynamic routing, fused per-sample. fp32 I/O:
// x: f32 [8192, 32, 8], W: f32 [32, 8, 256], out: f32 [8192, 16, 16].
// One block = 2 samples packed as the two components of v2f lanes;
// thread t = (nc = t>>4, dc = t&15) owns output column k = t.
// u_hat registers hold the XOR-PERMUTED order uhx[icb+j] = uh[icb+(j^dc)]
// (permutation baked into the W-transpose gather), which makes the b_update
// transpose-reduction butterfly select-free:  y[j] += shfl_xor(y[j^k], k)
// with compile-time register indices. c.uh compensates by reading c at
// xored LDS indices (exact: sum is a permutation). f16 dot2 for u_hat.

#define S 2

typedef float    v2f __attribute__((ext_vector_type(2)));
typedef _Float16 v2h __attribute__((ext_vector_type(2)));

// DPP cross-lane: value of `x` from lane (lane ^ k) within a 16-lane row.
// 0xB1 = quad_perm[1,0,3,2] (xor1)  0x4E = quad_perm[2,3,0,1] (xor2)
// 0x128 = row_ror:8 (xor8)  0x141 = row_half_mirror  0x140 = row_mirror
template <int CTRL>
__device__ __forceinline__ float dppf(float x) {
  return __builtin_bit_cast(float,
      __builtin_amdgcn_update_dpp(0, __builtin_bit_cast(int, x), CTRL, 0xF, 0xF, true));
}
template <int CTRL>
__device__ __forceinline__ v2f dpp2(v2f v) {
  v2f r;
  r.x = dppf<CTRL>(v.x);
  r.y = dppf<CTRL>(v.y);
  return r;
}
// xor4 has no DPP encoding: ds_swizzle (BitMode: xor=4, and=0x1F)
__device__ __forceinline__ float swz4(float x) {
  return __builtin_bit_cast(float,
      __builtin_amdgcn_ds_swizzle(__builtin_bit_cast(int, x), 0x101F));
}
__device__ __forceinline__ v2f swz4_2(v2f v) {
  v2f r;
  r.x = swz4(v.x);
  r.y = swz4(v.y);
  return r;
}

#if __has_builtin(__builtin_amdgcn_fdot2)
__device__ __forceinline__ float dot2(v2h a, v2h b, float c) {
  return __builtin_amdgcn_fdot2(a, b, c, false);  // v_dot2_f32_f16
}
#else
__device__ __forceinline__ float dot2(v2h a, v2h b, float c) {
  return fmaf((float)a.x, (float)b.x, fmaf((float)a.y, (float)b.y, c));
}
#endif

// W[ic][id][k] (f32) -> Wth[ic_slot][k][id] (f16) with the xor pre-permute:
// slot (icb + j) at column k holds W row icb + (j ^ (k & 15)).
__global__ __launch_bounds__(256) void wt_kernel(const float* __restrict__ W,
                                                 _Float16* __restrict__ Wth) {
  int o       = blockIdx.x * 256 + threadIdx.x;  // 65536 total
  int ic_slot = o >> 11;
  int k       = (o >> 3) & 255;
  int id      = o & 7;
  int ic_src  = (ic_slot & 16) | ((ic_slot ^ k) & 15);
  Wth[o] = (_Float16)W[(ic_src * 8 + id) * 256 + k];
}

// x (f32, 2M elems) -> xh (f16), same layout; 8 elems/thread
__global__ __launch_bounds__(256) void xh_kernel(const float* __restrict__ x,
                                                 _Float16* __restrict__ xh) {
  int tid = blockIdx.x * 256 + threadIdx.x;
  const float4* xp = (const float4*)x + tid * 2;
  float4 f0 = xp[0], f1 = xp[1];
  v2h h0 = {(_Float16)f0.x, (_Float16)f0.y};
  v2h h1 = {(_Float16)f0.z, (_Float16)f0.w};
  v2h h2 = {(_Float16)f1.x, (_Float16)f1.y};
  v2h h3 = {(_Float16)f1.z, (_Float16)f1.w};
  uint4 o;
  o.x = __builtin_bit_cast(unsigned, h0);
  o.y = __builtin_bit_cast(unsigned, h1);
  o.z = __builtin_bit_cast(unsigned, h2);
  o.w = __builtin_bit_cast(unsigned, h3);
  ((uint4*)xh)[tid] = o;
}

// squash over the 16 dc lanes, both samples at once; DPP-only reduction.
__device__ __forceinline__ v2f squash2(v2f o) {
  v2f s2 = o * o;
  s2 += dpp2<0xB1>(s2);   // + lane^1
  s2 += dpp2<0x4E>(s2);   // + lane^2
  s2 += dpp2<0x141>(s2);  // + lane^7 (row_half_mirror)
  s2 += dpp2<0x140>(s2);  // + lane^15 (row_mirror)
  s2 += (v2f){1e-7f, 1e-7f};
  v2f sc;
  sc.x = s2.x * __builtin_amdgcn_rsqf(s2.x) * __builtin_amdgcn_rcpf(1.f + s2.x);
  sc.y = s2.y * __builtin_amdgcn_rsqf(s2.y) * __builtin_amdgcn_rcpf(1.f + s2.y);
  return o * sc;  // sqrt(s2)/(1+s2) * o
}

// Select-free butterfly on xor-permuted uhx: y[j] = v*uhx[icb+j], then
// y[j] += shfl_xor(y[j^k], k) for k = 8,4,2,1 (halving live set).
// Invariant: after step k, y[j] = sum over lane-group {l ^ spans} of
// v*uh[icb + (j ^ l)]; y[0] at lane dc = sum_dc' v*uh[icb+dc]. Lane dc
// writes b[icb+dc] for both samples.
template <bool ASSIGN>
__device__ __forceinline__ void b_update2(v2f v, const v2f* uhx, int dc,
                                          float* bp0, float* bp1) {
#pragma unroll
  for (int icb = 0; icb < 32; icb += 16) {
    v2f y[16];
#pragma unroll
    for (int j = 0; j < 16; ++j) y[j] = v * uhx[icb + j];  // pk_mul
#pragma unroll
    for (int j = 0; j < 8; ++j) y[j] += dpp2<0x128>(y[j + 8]);  // xor8
#pragma unroll
    for (int j = 0; j < 4; ++j) y[j] += swz4_2(y[j + 4]);       // xor4 (DS)
#pragma unroll
    for (int j = 0; j < 2; ++j) y[j] += dpp2<0x4E>(y[j + 2]);   // xor2
    y[0] += dpp2<0xB1>(y[1]);                                   // xor1
    if (ASSIGN) { bp0[icb + dc] = y[0].x;  bp1[icb + dc] = y[0].y; }
    else        { bp0[icb + dc] += y[0].x; bp1[icb + dc] += y[0].y; }
  }
}

__global__ __launch_bounds__(256, 3) void caps_kernel(const _Float16* __restrict__ xh,
                                                      const uint4* __restrict__ Wt4,
                                                      float* __restrict__ out) {
  const int t  = threadIdx.x;
  const int nc = t >> 4;
  const int dc = t & 15;
  const int s0 = blockIdx.x * S;

  __shared__ float b_lds[S][16][33];  // +1 pad: nc-column reads conflict-free
  __shared__ float c_lds[16][66];     // c[n][2*ic+s] (float2 per ic), 66 = pad

  v2f uhx[32];                        // xor-permuted: uhx[icb+j] = uh[icb+(j^dc)]
  v2f o2 = (v2f){0.f, 0.f};

  // ---- u_hat (xor order comes from the W layout); round-0 sum fused ----
  const v2h* xp0 = (const v2h*)(xh + (s0 + 0) * 256);  // block-uniform -> s_load
  const v2h* xp1 = (const v2h*)(xh + (s0 + 1) * 256);
#pragma unroll
  for (int ic = 0; ic < 32; ++ic) {
    uint4 wv = Wt4[ic * 256 + t];  // 8 f16 weights, one coalesced dwordx4
    v2h w0 = __builtin_bit_cast(v2h, wv.x);
    v2h w1 = __builtin_bit_cast(v2h, wv.y);
    v2h w2 = __builtin_bit_cast(v2h, wv.z);
    v2h w3 = __builtin_bit_cast(v2h, wv.w);
    // source W row for this lane is (ic&16) + ((ic^dc)&15): x indices follow
    const int icx0 = (ic & 16) | ((ic ^ dc) & 15);
    float a0 = dot2(xp0[icx0 * 4 + 3], w3,
               dot2(xp0[icx0 * 4 + 2], w2,
               dot2(xp0[icx0 * 4 + 1], w1,
               dot2(xp0[icx0 * 4 + 0], w0, 0.f))));
    float a1 = dot2(xp1[icx0 * 4 + 3], w3,
               dot2(xp1[icx0 * 4 + 2], w2,
               dot2(xp1[icx0 * 4 + 1], w1,
               dot2(xp1[icx0 * 4 + 0], w0, 0.f))));
    v2f u = (v2f){a0, a1};
    uhx[ic] = u;
    o2 += u;  // permutation-invariant sum
  }

  // ---- routing round 0: b = 0 => c = 1/16 ----
  {
    v2f v = squash2(o2 * (v2f){0.0625f, 0.0625f});
    b_update2<true>(v, uhx, dc, &b_lds[0][nc][0], &b_lds[1][nc][0]);
  }
  __syncthreads();

  // ---- rounds 1, 2 ----
#pragma unroll
  for (int r = 1; r < 3; ++r) {
    {  // distributed softmax over nc: all 256 threads. thread -> (s, ic, quarter)
      const int ss  = t >> 7;         // sample
      const int icc = (t >> 2) & 31;  // column
      const int q   = t & 3;          // rows 4q..4q+3
      // no max-subtraction: |b| bounded far below exp overflow; shift-invariant.
      float e0 = __expf(b_lds[ss][4 * q + 0][icc]);
      float e1 = __expf(b_lds[ss][4 * q + 1][icc]);
      float e2 = __expf(b_lds[ss][4 * q + 2][icc]);
      float e3 = __expf(b_lds[ss][4 * q + 3][icc]);
      float ps = (e0 + e1) + (e2 + e3);
      ps += dppf<0xB1>(ps);  // + lane^1 (quad)
      ps += dppf<0x4E>(ps);  // + lane^2 (quad) -> full 16-row sum
      float inv = __builtin_amdgcn_rcpf(ps);
      c_lds[4 * q + 0][2 * icc + ss] = e0 * inv;
      c_lds[4 * q + 1][2 * icc + ss] = e1 * inv;
      c_lds[4 * q + 2][2 * icc + ss] = e2 * inv;
      c_lds[4 * q + 3][2 * icc + ss] = e3 * inv;
    }
    __syncthreads();

    // c.uh on xor-permuted uhx: sum_j c[j^dc]*uh[j^dc] == sum_m c[m]*uh[m]
    const float2* cpair = (const float2*)&c_lds[nc][0];  // [ic] -> {c0,c1}
    v2f o = (v2f){0.f, 0.f};
#pragma unroll
    for (int j = 0; j < 16; ++j) {
      const int m = j ^ dc;
      float2 cA = cpair[m];       // icb = 0
      float2 cB = cpair[m + 16];  // icb = 16
      o = __builtin_elementwise_fma((v2f){cA.x, cA.y}, uhx[j], o);
      o = __builtin_elementwise_fma((v2f){cB.x, cB.y}, uhx[16 + j], o);
    }
    v2f v = squash2(o);
    if (r == 2) {
      out[(s0 + 0) * 256 + t] = v.x;
      out[(s0 + 1) * 256 + t] = v.y;
    } else {
      b_update2<false>(v, uhx, dc, &b_lds[0][nc][0], &b_lds[1][nc][0]);
      __syncthreads();  // b complete before round-2 softmax; c overwrite safe
    }
  }
}

extern "C" void kernel_launch(void* const* d_in, const int* in_sizes, int n_in,
                              void* d_out, int out_size, void* d_ws, size_t ws_size,
                              hipStream_t stream) {
  const float* x = (const float*)d_in[0];
  const float* W = (const float*)d_in[1];
  _Float16* Wth = (_Float16*)d_ws;           // 128 KB: f16 W-transpose (xor order)
  _Float16* xh  = (_Float16*)d_ws + 65536;   // 4 MB: f16 x

  wt_kernel<<<256, 256, 0, stream>>>(W, Wth);
  xh_kernel<<<1024, 256, 0, stream>>>(x, xh);
  caps_kernel<<<8192 / S, 256, 0, stream>>>(xh, (const uint4*)Wth, (float*)d_out);
}

// Round 10
// 98.076 us; speedup vs baseline: 1.1403x; 1.1403x over previous
//
#include <hip/hip_runtime.h>
#include <hip/hip_bf16.h>

// CapsuleNet dynamic routing, fused per-sample. fp32 I/O:
// x: f32 [8192, 32, 8], W: f32 [32, 8, 256], out: f32 [8192, 16, 16].
// One block = 2 samples packed as the two components of v2f lanes;
// thread t = (nc = t>>4, dc = t&15) owns output column k = t.
// u_hat in registers (v2f uh2[32]); x reads are WAVE-UNIFORM scalar loads.
// f16 dot2 for u_hat. Butterfly levels 8/2/1 via DPP xor-exchanges; level 4
// via dual bank-masked DPP shifts. r9 BUG FIX: banks 0,2 receive the
// partner's LO half (partner u4=1 sends b8[j]) via row_shl:4, banks 1,3
// receive the partner's HI half via row_shr:4 — halves were swapped in r9.

#define S 2

typedef float    v2f __attribute__((ext_vector_type(2)));
typedef _Float16 v2h __attribute__((ext_vector_type(2)));

// DPP cross-lane: value of `x` from lane (lane ^ k) within a 16-lane row.
// 0xB1 = quad_perm[1,0,3,2] (xor1)  0x4E = quad_perm[2,3,0,1] (xor2)
// 0x128 = row_ror:8 (xor8)  0x141 = row_half_mirror  0x140 = row_mirror
template <int CTRL>
__device__ __forceinline__ float dppf(float x) {
  return __builtin_bit_cast(float,
      __builtin_amdgcn_update_dpp(0, __builtin_bit_cast(int, x), CTRL, 0xF, 0xF, true));
}
template <int CTRL>
__device__ __forceinline__ v2f dpp2(v2f v) {
  v2f r;
  r.x = dppf<CTRL>(v.x);
  r.y = dppf<CTRL>(v.y);
  return r;
}
// Masked DPP keeping `old` on disabled banks (bound_ctrl=false: keep old).
template <int CTRL, int BANK>
__device__ __forceinline__ float dpp_old(float old, float x) {
  return __builtin_bit_cast(float,
      __builtin_amdgcn_update_dpp(__builtin_bit_cast(int, old),
                                  __builtin_bit_cast(int, x), CTRL, 0xF, BANK, false));
}
// recv for the xor4 exchange. Reference (validated swz4 path): lane with
// u4=0 receives partner(lane+4)'s send = partner's b8[j]   (= lo);
// lane with u4=1 receives partner(lane-4)'s send = partner's b8[j+4] (= hi).
// row_shr:N = receive from lane-N (LLVM DPP scan convention), row_shl:N =
// receive from lane+N. banks: 0=lanes0-3,1=4-7,2=8-11,3=12-15 per 16-row.
__device__ __forceinline__ float xor4_recv(float lo /*b8[j]*/, float hi /*b8[j+4]*/) {
  float ya = dpp_old<0x104, 0x5>(0.0f, lo);  // banks 0,2 <- (lane+4)'s lo
  return dpp_old<0x114, 0xA>(ya, hi);        // banks 1,3 <- (lane-4)'s hi
}

#if __has_builtin(__builtin_amdgcn_fdot2)
__device__ __forceinline__ float dot2(v2h a, v2h b, float c) {
  return __builtin_amdgcn_fdot2(a, b, c, false);  // v_dot2_f32_f16
}
#else
__device__ __forceinline__ float dot2(v2h a, v2h b, float c) {
  return fmaf((float)a.x, (float)b.x, fmaf((float)a.y, (float)b.y, c));
}
#endif

// Fused prep: blocks 0..255 transpose W[ic][id][k](f32) -> Wth[ic][k][id](f16);
// blocks 256..1279 convert x (f32) -> xh (f16), 8 elems/thread.
__global__ __launch_bounds__(256) void prep_kernel(const float* __restrict__ W,
                                                   const float* __restrict__ x,
                                                   _Float16* __restrict__ Wth,
                                                   _Float16* __restrict__ xh) {
  int bid = blockIdx.x;
  if (bid < 256) {
    int o  = bid * 256 + threadIdx.x;
    int ic = o >> 11;
    int k  = (o >> 3) & 255;
    int id = o & 7;
    Wth[o] = (_Float16)W[(ic * 8 + id) * 256 + k];
  } else {
    int tid = (bid - 256) * 256 + threadIdx.x;
    const float4* xp = (const float4*)x + tid * 2;
    float4 f0 = xp[0], f1 = xp[1];
    v2h h0 = {(_Float16)f0.x, (_Float16)f0.y};
    v2h h1 = {(_Float16)f0.z, (_Float16)f0.w};
    v2h h2 = {(_Float16)f1.x, (_Float16)f1.y};
    v2h h3 = {(_Float16)f1.z, (_Float16)f1.w};
    uint4 o;
    o.x = __builtin_bit_cast(unsigned, h0);
    o.y = __builtin_bit_cast(unsigned, h1);
    o.z = __builtin_bit_cast(unsigned, h2);
    o.w = __builtin_bit_cast(unsigned, h3);
    ((uint4*)xh)[tid] = o;
  }
}

// squash over the 16 dc lanes, both samples at once; DPP-only reduction.
__device__ __forceinline__ v2f squash2(v2f o) {
  v2f s2 = o * o;
  s2 += dpp2<0xB1>(s2);   // + lane^1
  s2 += dpp2<0x4E>(s2);   // + lane^2
  s2 += dpp2<0x141>(s2);  // + lane^7 (row_half_mirror)
  s2 += dpp2<0x140>(s2);  // + lane^15 (row_mirror)
  s2 += (v2f){1e-7f, 1e-7f};
  v2f sc;
  sc.x = s2.x * __builtin_amdgcn_rsqf(s2.x) * __builtin_amdgcn_rcpf(1.f + s2.x);
  sc.y = s2.y * __builtin_amdgcn_rsqf(s2.y) * __builtin_amdgcn_rcpf(1.f + s2.y);
  return o * sc;  // sqrt(s2)/(1+s2) * o
}

// b[nc][ic] (=/+=) sum_dc v*uh[ic], both samples packed, via butterfly
// transpose-reduction over the 16 dc lanes; lane dc lands ic = icb + dc.
// Levels 8/2/1 via DPP xor; level 4 via dual bank-masked DPP shifts.
template <bool ASSIGN>
__device__ __forceinline__ void b_update2(v2f v, const v2f* uh2, int dc,
                                          float* bp0, float* bp1) {
#pragma unroll
  for (int icb = 0; icb < 32; icb += 16) {
    v2f a[16];
#pragma unroll
    for (int j = 0; j < 16; ++j) a[j] = v * uh2[icb + j];  // pk_mul
    v2f b8[8];
    const bool u8 = (dc & 8) != 0;
#pragma unroll
    for (int j = 0; j < 8; ++j) {
      v2f send = u8 ? a[j] : a[j + 8];
      v2f recv = dpp2<0x128>(send);          // exchange with lane^8
      b8[j] = (u8 ? a[j + 8] : a[j]) + recv;
    }
    v2f c4[4];
    const bool u4 = (dc & 4) != 0;
#pragma unroll
    for (int j = 0; j < 4; ++j) {
      v2f recv;
      recv.x = xor4_recv(b8[j].x, b8[j + 4].x);  // partner's send value
      recv.y = xor4_recv(b8[j].y, b8[j + 4].y);
      c4[j] = (u4 ? b8[j + 4] : b8[j]) + recv;
    }
    v2f d2[2];
    const bool u2 = (dc & 2) != 0;
#pragma unroll
    for (int j = 0; j < 2; ++j) {
      v2f send = u2 ? c4[j] : c4[j + 2];
      v2f recv = dpp2<0x4E>(send);           // exchange with lane^2
      d2[j] = (u2 ? c4[j + 2] : c4[j]) + recv;
    }
    const bool u1 = (dc & 1) != 0;
    v2f send = u1 ? d2[0] : d2[1];
    v2f recv = dpp2<0xB1>(send);             // exchange with lane^1
    v2f e = (u1 ? d2[1] : d2[0]) + recv;
    if (ASSIGN) { bp0[icb + dc] = e.x;  bp1[icb + dc] = e.y; }
    else        { bp0[icb + dc] += e.x; bp1[icb + dc] += e.y; }
  }
}

__global__ __launch_bounds__(256, 3) void caps_kernel(const _Float16* __restrict__ xh,
                                                      const uint4* __restrict__ Wt4,
                                                      float* __restrict__ out) {
  const int t  = threadIdx.x;
  const int nc = t >> 4;
  const int dc = t & 15;
  const int s0 = blockIdx.x * S;

  __shared__ float b_lds[S][16][33];             // +1 pad: nc-column reads conflict-free
  __shared__ __align__(16) float c_lds[16][68];  // c[n][2*ic+s]; 68: 16q -> 2-way max

  v2f uh2[32];
  v2f o2 = (v2f){0.f, 0.f};

  // ---- u_hat: uh2[ic] = {dot(u_s0, W), dot(u_s1, W)}; round-0 sum fused ----
  const v2h* xp0 = (const v2h*)(xh + (s0 + 0) * 256);  // block-uniform -> s_load
  const v2h* xp1 = (const v2h*)(xh + (s0 + 1) * 256);
#pragma unroll
  for (int ic = 0; ic < 32; ++ic) {
    uint4 wv = Wt4[ic * 256 + t];  // 8 f16 weights, one coalesced dwordx4
    v2h w0 = __builtin_bit_cast(v2h, wv.x);
    v2h w1 = __builtin_bit_cast(v2h, wv.y);
    v2h w2 = __builtin_bit_cast(v2h, wv.z);
    v2h w3 = __builtin_bit_cast(v2h, wv.w);
    float a0 = dot2(xp0[ic * 4 + 3], w3,
               dot2(xp0[ic * 4 + 2], w2,
               dot2(xp0[ic * 4 + 1], w1,
               dot2(xp0[ic * 4 + 0], w0, 0.f))));
    float a1 = dot2(xp1[ic * 4 + 3], w3,
               dot2(xp1[ic * 4 + 2], w2,
               dot2(xp1[ic * 4 + 1], w1,
               dot2(xp1[ic * 4 + 0], w0, 0.f))));
    v2f u = (v2f){a0, a1};
    uh2[ic] = u;
    o2 += u;
  }

  // ---- routing round 0: b = 0 => c = 1/16 ----
  {
    v2f v = squash2(o2 * (v2f){0.0625f, 0.0625f});
    b_update2<true>(v, uh2, dc, &b_lds[0][nc][0], &b_lds[1][nc][0]);
  }
  __syncthreads();

  // ---- rounds 1, 2 ----
#pragma unroll
  for (int r = 1; r < 3; ++r) {
    {  // distributed softmax over nc: all 256 threads. thread -> (s, ic, quarter)
      const int ss  = t >> 7;         // sample
      const int icc = (t >> 2) & 31;  // column
      const int q   = t & 3;          // rows 4q..4q+3
      // no max-subtraction: |b| bounded far below exp overflow; shift-invariant.
      float e0 = __expf(b_lds[ss][4 * q + 0][icc]);
      float e1 = __expf(b_lds[ss][4 * q + 1][icc]);
      float e2 = __expf(b_lds[ss][4 * q + 2][icc]);
      float e3 = __expf(b_lds[ss][4 * q + 3][icc]);
      float ps = (e0 + e1) + (e2 + e3);
      ps += dppf<0xB1>(ps);  // + lane^1 (quad)
      ps += dppf<0x4E>(ps);  // + lane^2 (quad) -> full 16-row sum
      float inv = __builtin_amdgcn_rcpf(ps);
      c_lds[4 * q + 0][2 * icc + ss] = e0 * inv;
      c_lds[4 * q + 1][2 * icc + ss] = e1 * inv;
      c_lds[4 * q + 2][2 * icc + ss] = e2 * inv;
      c_lds[4 * q + 3][2 * icc + ss] = e3 * inv;
    }
    __syncthreads();

    const float4* cp = (const float4*)&c_lds[nc][0];  // {c0[2j],c1[2j],c0[2j+1],c1[2j+1]}
    v2f o = (v2f){0.f, 0.f};
#pragma unroll
    for (int j = 0; j < 16; ++j) {
      float4 cc = cp[j];
      o = __builtin_elementwise_fma((v2f){cc.x, cc.y}, uh2[2 * j + 0], o);
      o = __builtin_elementwise_fma((v2f){cc.z, cc.w}, uh2[2 * j + 1], o);
    }
    v2f v = squash2(o);
    if (r == 2) {
      out[(s0 + 0) * 256 + t] = v.x;
      out[(s0 + 1) * 256 + t] = v.y;
    } else {
      b_update2<false>(v, uh2, dc, &b_lds[0][nc][0], &b_lds[1][nc][0]);
    }
    __syncthreads();  // b complete before round-2 softmax; c safe to overwrite
  }
}

extern "C" void kernel_launch(void* const* d_in, const int* in_sizes, int n_in,
                              void* d_out, int out_size, void* d_ws, size_t ws_size,
                              hipStream_t stream) {
  const float* x = (const float*)d_in[0];
  const float* W = (const float*)d_in[1];
  _Float16* Wth = (_Float16*)d_ws;           // 128 KB: f16 W-transpose
  _Float16* xh  = (_Float16*)d_ws + 65536;   // 4 MB: f16 x

  prep_kernel<<<1280, 256, 0, stream>>>(W, x, Wth, xh);
  caps_kernel<<<8192 / S, 256, 0, stream>>>(xh, (const uint4*)Wth, (float*)d_out);
}

// Round 11
// 97.251 us; speedup vs baseline: 1.1500x; 1.0085x over previous
//
#include <hip/hip_runtime.h>
#include <hip/hip_bf16.h>

// CapsuleNet dynamic routing, fused per-sample. fp32 I/O:
// x: f32 [8192, 32, 8], W: f32 [32, 8, 256], out: f32 [8192, 16, 16].
// One block = 2 samples packed as the two components of v2f lanes;
// thread t = (nc = t>>4, dc = t&15) owns output column k = t.
// u_hat registers hold the XOR-PERMUTED order uhx[icb+j] = uh[icb+(j^dc)]
// (permutation baked into the W-transpose gather; proven correct in the
// earlier xor-permute run), making the b_update butterfly SELECT-FREE:
// y[j] += transport(y[j+k]) with compile-time register indices, xor8/2/1 as
// fusable v_add_f32_dpp, xor4 via the (proven) dual bank-masked DPP shifts.
// x cost fix vs the old xor-permute attempt: block's 512 xh values staged
// into LDS (coalesced) so the lane-dependent read is a ds_read_b128 on the
// DS pipe (parallel to VALU), not a scattered global load.

#define S 2

typedef float    v2f __attribute__((ext_vector_type(2)));
typedef _Float16 v2h __attribute__((ext_vector_type(2)));

// DPP cross-lane: value of `x` from lane (lane ^ k) within a 16-lane row.
// 0xB1 = quad_perm[1,0,3,2] (xor1)  0x4E = quad_perm[2,3,0,1] (xor2)
// 0x128 = row_ror:8 (xor8)  0x141 = row_half_mirror  0x140 = row_mirror
template <int CTRL>
__device__ __forceinline__ float dppf(float x) {
  return __builtin_bit_cast(float,
      __builtin_amdgcn_update_dpp(0, __builtin_bit_cast(int, x), CTRL, 0xF, 0xF, true));
}
template <int CTRL>
__device__ __forceinline__ v2f dpp2(v2f v) {
  v2f r;
  r.x = dppf<CTRL>(v.x);
  r.y = dppf<CTRL>(v.y);
  return r;
}
// Masked DPP keeping `old` on disabled banks (bound_ctrl=false: keep old).
template <int CTRL, int BANK>
__device__ __forceinline__ float dpp_old(float old, float x) {
  return __builtin_bit_cast(float,
      __builtin_amdgcn_update_dpp(__builtin_bit_cast(int, old),
                                  __builtin_bit_cast(int, x), CTRL, 0xF, BANK, false));
}
// Transport s from lane^4 to every lane (validated in r10's fixed xor4):
// banks 0,2 (lanes 0-3,8-11): from lane+4 via row_shl:4 (0x104);
// banks 1,3 (lanes 4-7,12-15): from lane-4 via row_shr:4 (0x114).
__device__ __forceinline__ float xor4t(float s) {
  float ya = dpp_old<0x104, 0x5>(0.0f, s);
  return dpp_old<0x114, 0xA>(ya, s);
}

#if __has_builtin(__builtin_amdgcn_fdot2)
__device__ __forceinline__ float dot2(v2h a, v2h b, float c) {
  return __builtin_amdgcn_fdot2(a, b, c, false);  // v_dot2_f32_f16
}
#else
__device__ __forceinline__ float dot2(v2h a, v2h b, float c) {
  return fmaf((float)a.x, (float)b.x, fmaf((float)a.y, (float)b.y, c));
}
#endif

// Fused prep: blocks 0..255: W[ic][id][k](f32) -> Wth[ic_slot][k][id](f16)
// with the xor pre-permute (slot icb+j at column k holds row icb+(j^(k&15)));
// blocks 256..1279: x (f32) -> xh (f16), 8 elems/thread.
__global__ __launch_bounds__(256) void prep_kernel(const float* __restrict__ W,
                                                   const float* __restrict__ x,
                                                   _Float16* __restrict__ Wth,
                                                   _Float16* __restrict__ xh) {
  int bid = blockIdx.x;
  if (bid < 256) {
    int o       = bid * 256 + threadIdx.x;
    int ic_slot = o >> 11;
    int k       = (o >> 3) & 255;
    int id      = o & 7;
    int ic_src  = (ic_slot & 16) | ((ic_slot ^ k) & 15);
    Wth[o] = (_Float16)W[(ic_src * 8 + id) * 256 + k];
  } else {
    int tid = (bid - 256) * 256 + threadIdx.x;
    const float4* xp = (const float4*)x + tid * 2;
    float4 f0 = xp[0], f1 = xp[1];
    v2h h0 = {(_Float16)f0.x, (_Float16)f0.y};
    v2h h1 = {(_Float16)f0.z, (_Float16)f0.w};
    v2h h2 = {(_Float16)f1.x, (_Float16)f1.y};
    v2h h3 = {(_Float16)f1.z, (_Float16)f1.w};
    uint4 o;
    o.x = __builtin_bit_cast(unsigned, h0);
    o.y = __builtin_bit_cast(unsigned, h1);
    o.z = __builtin_bit_cast(unsigned, h2);
    o.w = __builtin_bit_cast(unsigned, h3);
    ((uint4*)xh)[tid] = o;
  }
}

// squash over the 16 dc lanes, both samples at once; DPP-only reduction.
__device__ __forceinline__ v2f squash2(v2f o) {
  v2f s2 = o * o;
  s2.x += dppf<0xB1>(s2.x);   s2.y += dppf<0xB1>(s2.y);    // + lane^1
  s2.x += dppf<0x4E>(s2.x);   s2.y += dppf<0x4E>(s2.y);    // + lane^2
  s2.x += dppf<0x141>(s2.x);  s2.y += dppf<0x141>(s2.y);   // + lane^7
  s2.x += dppf<0x140>(s2.x);  s2.y += dppf<0x140>(s2.y);   // + lane^15
  s2 += (v2f){1e-7f, 1e-7f};
  v2f sc;
  sc.x = s2.x * __builtin_amdgcn_rsqf(s2.x) * __builtin_amdgcn_rcpf(1.f + s2.x);
  sc.y = s2.y * __builtin_amdgcn_rsqf(s2.y) * __builtin_amdgcn_rcpf(1.f + s2.y);
  return o * sc;  // sqrt(s2)/(1+s2) * o
}

// Select-free butterfly on xor-permuted uhx (proven layout): lane dc lands
// b[icb+dc] for both samples. xor8/2/1 as scalar adds (fusable to
// v_add_f32_dpp); xor4 via the masked dual-DPP transport.
template <bool ASSIGN>
__device__ __forceinline__ void b_update2(v2f v, const v2f* uhx, int dc,
                                          float* bp0, float* bp1) {
#pragma unroll
  for (int icb = 0; icb < 32; icb += 16) {
    v2f y[16];
#pragma unroll
    for (int j = 0; j < 16; ++j) y[j] = v * uhx[icb + j];  // pk_mul
#pragma unroll
    for (int j = 0; j < 8; ++j) {  // + value from lane^8
      y[j].x += dppf<0x128>(y[j + 8].x);
      y[j].y += dppf<0x128>(y[j + 8].y);
    }
#pragma unroll
    for (int j = 0; j < 4; ++j) {  // + value from lane^4
      y[j].x += xor4t(y[j + 4].x);
      y[j].y += xor4t(y[j + 4].y);
    }
#pragma unroll
    for (int j = 0; j < 2; ++j) {  // + value from lane^2
      y[j].x += dppf<0x4E>(y[j + 2].x);
      y[j].y += dppf<0x4E>(y[j + 2].y);
    }
    y[0].x += dppf<0xB1>(y[1].x);  // + value from lane^1
    y[0].y += dppf<0xB1>(y[1].y);
    if (ASSIGN) { bp0[icb + dc] = y[0].x;  bp1[icb + dc] = y[0].y; }
    else        { bp0[icb + dc] += y[0].x; bp1[icb + dc] += y[0].y; }
  }
}

__global__ __launch_bounds__(256, 3) void caps_kernel(const unsigned* __restrict__ xh32,
                                                      const uint4* __restrict__ Wt4,
                                                      float* __restrict__ out) {
  const int t  = threadIdx.x;
  const int nc = t >> 4;
  const int dc = t & 15;
  const int s0 = blockIdx.x * S;

  __shared__ float b_lds[S][16][33];  // +1 pad: nc-column reads conflict-free
  __shared__ float c_lds[16][66];     // c[n][2*ic+s] (float2 per ic)
  __shared__ __align__(16) _Float16 xh_lds[2 * 256];  // block's x, f16

  // ---- stage this block's x slice into LDS (coalesced dword copy) ----
  ((unsigned*)xh_lds)[t] = xh32[s0 * 128 + t];
  __syncthreads();

  v2f uhx[32];                        // xor-permuted: uhx[icb+j] = uh[icb+(j^dc)]
  v2f o2 = (v2f){0.f, 0.f};

  // ---- u_hat (xor order from the W layout); x rows via ds_read_b128 ----
#pragma unroll
  for (int ic = 0; ic < 32; ++ic) {
    uint4 wv = Wt4[ic * 256 + t];  // 8 f16 weights, one coalesced dwordx4
    v2h w0 = __builtin_bit_cast(v2h, wv.x);
    v2h w1 = __builtin_bit_cast(v2h, wv.y);
    v2h w2 = __builtin_bit_cast(v2h, wv.z);
    v2h w3 = __builtin_bit_cast(v2h, wv.w);
    const int icx0 = (ic & 16) | ((ic ^ dc) & 15);  // source x row for this lane
    uint4 xv0 = *(const uint4*)(xh_lds + icx0 * 8);        // sample 0, 8 f16
    uint4 xv1 = *(const uint4*)(xh_lds + 256 + icx0 * 8);  // sample 1
    float a0 = dot2(__builtin_bit_cast(v2h, xv0.w), w3,
               dot2(__builtin_bit_cast(v2h, xv0.z), w2,
               dot2(__builtin_bit_cast(v2h, xv0.y), w1,
               dot2(__builtin_bit_cast(v2h, xv0.x), w0, 0.f))));
    float a1 = dot2(__builtin_bit_cast(v2h, xv1.w), w3,
               dot2(__builtin_bit_cast(v2h, xv1.z), w2,
               dot2(__builtin_bit_cast(v2h, xv1.y), w1,
               dot2(__builtin_bit_cast(v2h, xv1.x), w0, 0.f))));
    v2f u = (v2f){a0, a1};
    uhx[ic] = u;
    o2 += u;  // permutation-invariant sum
  }

  // ---- routing round 0: b = 0 => c = 1/16 ----
  {
    v2f v = squash2(o2 * (v2f){0.0625f, 0.0625f});
    b_update2<true>(v, uhx, dc, &b_lds[0][nc][0], &b_lds[1][nc][0]);
  }
  __syncthreads();

  // ---- rounds 1, 2 ----
#pragma unroll
  for (int r = 1; r < 3; ++r) {
    {  // distributed softmax over nc: all 256 threads. thread -> (s, ic, quarter)
      const int ss  = t >> 7;         // sample
      const int icc = (t >> 2) & 31;  // column
      const int q   = t & 3;          // rows 4q..4q+3
      // no max-subtraction: |b| bounded far below exp overflow; shift-invariant.
      float e0 = __expf(b_lds[ss][4 * q + 0][icc]);
      float e1 = __expf(b_lds[ss][4 * q + 1][icc]);
      float e2 = __expf(b_lds[ss][4 * q + 2][icc]);
      float e3 = __expf(b_lds[ss][4 * q + 3][icc]);
      float ps = (e0 + e1) + (e2 + e3);
      ps += dppf<0xB1>(ps);  // + lane^1 (quad)
      ps += dppf<0x4E>(ps);  // + lane^2 (quad) -> full 16-row sum
      float inv = __builtin_amdgcn_rcpf(ps);
      c_lds[4 * q + 0][2 * icc + ss] = e0 * inv;
      c_lds[4 * q + 1][2 * icc + ss] = e1 * inv;
      c_lds[4 * q + 2][2 * icc + ss] = e2 * inv;
      c_lds[4 * q + 3][2 * icc + ss] = e3 * inv;
    }
    __syncthreads();

    // c.uh on xor-permuted uhx: sum_j c[j^dc]*uh[j^dc] == sum_m c[m]*uh[m]
    const float2* cpair = (const float2*)&c_lds[nc][0];  // [ic] -> {c0,c1}
    v2f o = (v2f){0.f, 0.f};
#pragma unroll
    for (int j = 0; j < 16; ++j) {
      const int m = j ^ dc;
      float2 cA = cpair[m];       // icb = 0
      float2 cB = cpair[m + 16];  // icb = 16
      o = __builtin_elementwise_fma((v2f){cA.x, cA.y}, uhx[j], o);
      o = __builtin_elementwise_fma((v2f){cB.x, cB.y}, uhx[16 + j], o);
    }
    v2f v = squash2(o);
    if (r == 2) {
      out[(s0 + 0) * 256 + t] = v.x;
      out[(s0 + 1) * 256 + t] = v.y;
    } else {
      b_update2<false>(v, uhx, dc, &b_lds[0][nc][0], &b_lds[1][nc][0]);
      __syncthreads();  // b complete before round-2 softmax; c overwrite safe
    }
  }
}

extern "C" void kernel_launch(void* const* d_in, const int* in_sizes, int n_in,
                              void* d_out, int out_size, void* d_ws, size_t ws_size,
                              hipStream_t stream) {
  const float* x = (const float*)d_in[0];
  const float* W = (const float*)d_in[1];
  _Float16* Wth = (_Float16*)d_ws;           // 128 KB: f16 W-transpose (xor order)
  _Float16* xh  = (_Float16*)d_ws + 65536;   // 4 MB: f16 x

  prep_kernel<<<1280, 256, 0, stream>>>(W, x, Wth, xh);
  caps_kernel<<<8192 / S, 256, 0, stream>>>((const unsigned*)xh, (const uint4*)Wth,
                                            (float*)d_out);
}